// Round 3
// baseline (139.223 us; speedup 1.0000x reference)
//
#include <hip/hip_runtime.h>
#include <math.h>

// Problem geometry
#define T_LEN   160000
#define NROW    128       // 64 rows of x then 64 rows of n
#define CHUNK   64        // samples per chunk (serial work per thread)
#define NCHUNK  2500      // CHUNK*NCHUNK == T_LEN
#define OWN     40        // chunks per lane in the scan (64*40 = 2560 >= 2500)

// HP biquad: y = x - 2 x1 + x2 + 1.99599 y1 - 0.996 y2
#define C1_HP ( 1.99599)
#define C2_HP (-0.996)

__device__ __forceinline__ float clip1f(float v) { return fminf(fmaxf(v, -1.0f), 1.0f); }

// ---------------------------------------------------------------------------
// pass_a1: per (row, chunk) LOCAL stage-1 end state (zero y-init, true x-hist).
// Reads x/n; writes only e1[row*NCHUNK + c] = (y[L-1], y[L-2])_local.
// ---------------------------------------------------------------------------
__global__ __launch_bounds__(256) void pass_a1(const float* __restrict__ x,
                                               const float* __restrict__ nn,
                                               double2* __restrict__ e1) {
  int g = blockIdx.x * blockDim.x + threadIdx.x;
  if (g >= NROW * NCHUNK) return;
  int row = g / NCHUNK, c = g % NCHUNK;
  const float* src = (row < 64) ? (x + (size_t)row * T_LEN)
                                : (nn + (size_t)(row - 64) * T_LEN);
  const float* xp = src + c * CHUNK;
  double x1 = 0.0, x2 = 0.0;
  if (c) { x1 = (double)xp[-1]; x2 = (double)xp[-2]; }
  double y1 = 0.0, y2 = 0.0;
#pragma unroll
  for (int j = 0; j < CHUNK; j += 4) {
    float4 xv = *reinterpret_cast<const float4*>(xp + j);
#define A1STEP(XF) { double xt = (double)(XF); \
    double y = xt - 2.0 * x1 + x2 + C1_HP * y1 + C2_HP * y2; \
    x2 = x1; x1 = xt; y2 = y1; y1 = y; }
    A1STEP(xv.x) A1STEP(xv.y) A1STEP(xv.z) A1STEP(xv.w)
#undef A1STEP
  }
  e1[g] = make_double2(y1, y2);
}

// ---------------------------------------------------------------------------
// scan1: wave-parallel per-row combine, s_{c+1} = M s_c + e_c with constant
// M = A_hp^CHUNK (computed in-register from the p recurrence).
// One wave per row; lane owns OWN contiguous chunks; streams e twice to keep
// register pressure low. Emits chunk-START true states s[c].
// ---------------------------------------------------------------------------
__global__ __launch_bounds__(256) void scan1_kernel(const double2* __restrict__ e,
                                                    double2* __restrict__ s) {
  int tid = blockIdx.x * blockDim.x + threadIdx.x;
  int row = tid >> 6;
  int lane = tid & 63;
  if (row >= NROW) return;
  // p[k] = C1_HP p[k-1] + C2_HP p[k-2]; p[-1]=0, p[0]=1.
  double pm2 = 0.0, pm1 = 0.0, p0 = 1.0;   // p[k-2], p[k-1], p[k]
#pragma unroll
  for (int k = 1; k <= CHUNK; ++k) {
    double pn = C1_HP * p0 + C2_HP * pm1;
    pm2 = pm1; pm1 = p0; p0 = pn;
  }
  // A^L = [[p[L], -a2 p[L-1]], [p[L-1], -a2 p[L-2]]],  -a2 = C2_HP
  const double m00 = p0,  m01 = C2_HP * pm1;
  const double m10 = pm1, m11 = C2_HP * pm2;
  const double2* ep = e + (size_t)row * NCHUNK;
  const int base = lane * OWN;
  // local composition f = sum_j M^{OWN-1-j} e_{base+j}  (streaming)
  double f1 = 0.0, f2 = 0.0;
  for (int j = 0; j < OWN; ++j) {
    int c = base + j;
    double2 ev = (c < NCHUNK) ? ep[c] : make_double2(0.0, 0.0);
    double n1 = m00 * f1 + m01 * f2 + ev.x;
    double n2 = m10 * f1 + m11 * f2 + ev.y;
    f1 = n1; f2 = n2;
  }
  // B = M^OWN (OWN=40=8*5: compute by repeated squaring/multiply: 40 = 101000b)
  // simpler: B = M^8^5? do exponent by binary: 40 = 32+8
  double b00 = m00, b01 = m01, b10 = m10, b11 = m11; // M^1
  double r00 = 1.0, r01 = 0.0, r10 = 0.0, r11 = 1.0; // accum
  int e40 = OWN;
  while (e40) {
    if (e40 & 1) {
      double t00 = b00 * r00 + b01 * r10, t01 = b00 * r01 + b01 * r11;
      double t10 = b10 * r00 + b11 * r10, t11 = b10 * r01 + b11 * r11;
      r00 = t00; r01 = t01; r10 = t10; r11 = t11;
    }
    double q00 = b00 * b00 + b01 * b10, q01 = b00 * b01 + b01 * b11;
    double q10 = b10 * b00 + b11 * b10, q11 = b10 * b01 + b11 * b11;
    b00 = q00; b01 = q01; b10 = q10; b11 = q11;
    e40 >>= 1;
  }
  b00 = r00; b01 = r01; b10 = r10; b11 = r11;  // B = M^OWN
  // Kogge-Stone inclusive scan over lanes; B squares each step
  double v1 = f1, v2 = f2;
#pragma unroll
  for (int off = 1; off < 64; off <<= 1) {
    double u1 = __shfl_up(v1, off);
    double u2 = __shfl_up(v2, off);
    if (lane >= off) {
      v1 += b00 * u1 + b01 * u2;
      v2 += b10 * u1 + b11 * u2;
    }
    double q00 = b00 * b00 + b01 * b10, q01 = b00 * b01 + b01 * b11;
    double q10 = b10 * b00 + b11 * b10, q11 = b10 * b01 + b11 * b11;
    b00 = q00; b01 = q01; b10 = q10; b11 = q11;
  }
  // exclusive prefix = segment-start state for this lane
  double g1 = __shfl_up(v1, 1);
  double g2 = __shfl_up(v2, 1);
  if (lane == 0) { g1 = 0.0; g2 = 0.0; }
  // re-stream e to emit chunk-start states
  double2* sp = s + (size_t)row * NCHUNK;
  double s1v = g1, s2v = g2;
  for (int j = 0; j < OWN; ++j) {
    int c = base + j;
    if (c < NCHUNK) {
      sp[c] = make_double2(s1v, s2v);
      double2 ev = ep[c];
      double n1 = m00 * s1v + m01 * s2v + ev.x;
      double n2 = m10 * s1v + m11 * s2v + ev.y;
      s1v = n1; s2v = n2;
    }
  }
}

// ---------------------------------------------------------------------------
// pass_a2: per (row, chunk) final output.
// Warm-up over chunk c-1: stage-1 TRUE recurrence seeded with s1[c-1] (exact),
// stage-2 f32 recurrence from zero state (pole^64 ~ 7e-6 -> error < 3e-4).
// Then own chunk c: continue both recurrences, write clip(stage2) to out.
// Stage-2 x-history at warm-up start = clip(s1[c-1]) (exact FIR history).
// ---------------------------------------------------------------------------
__global__ __launch_bounds__(256) void pass_a2(const float* __restrict__ x,
                                               const float* __restrict__ nn,
                                               const double2* __restrict__ s1,
                                               float* __restrict__ out,
                                               const float* __restrict__ cx,
                                               const float* __restrict__ cn) {
  int g = blockIdx.x * blockDim.x + threadIdx.x;
  if (g >= NROW * NCHUNK) return;
  int row = g / NCHUNK, c = g % NCHUNK;
  const float* src = (row < 64) ? (x + (size_t)row * T_LEN)
                                : (nn + (size_t)(row - 64) * T_LEN);
  const float* cf = (row < 64) ? cx : cn;
  const float A1c = cf[0], A2c = cf[1], B1c = cf[2], B2c = cf[3];

  double y1 = 0.0, y2 = 0.0;   // stage-1 true state
  double x1 = 0.0, x2 = 0.0;   // stage-1 x history
  float v1 = 0.0f, v2 = 0.0f;  // stage-2 x (=clipped stage-1) history
  float z1 = 0.0f, z2 = 0.0f;  // stage-2 y state

#define STEP(XF, EMIT, OF) { double xt = (double)(XF); \
    double yy = xt - 2.0 * x1 + x2 + C1_HP * y1 + C2_HP * y2; \
    x2 = x1; x1 = xt; y2 = y1; y1 = yy; \
    float v = clip1f((float)yy); \
    float zz = v + B1c * v1 + B2c * v2 - A1c * z1 - A2c * z2; \
    v2 = v1; v1 = v; z2 = z1; z1 = zz; \
    if (EMIT) OF = clip1f(zz); }

  if (c) {
    double2 sp = s1[g - 1];
    y1 = sp.x; y2 = sp.y;            // true y[t0-1], y[t0-2] of chunk c-1
    v1 = clip1f((float)sp.x); v2 = clip1f((float)sp.y);
    const float* wp = src + (c - 1) * CHUNK;
    if (c >= 2) { x1 = (double)wp[-1]; x2 = (double)wp[-2]; }
    float dummy;
#pragma unroll
    for (int j = 0; j < CHUNK; j += 4) {
      float4 xv = *reinterpret_cast<const float4*>(wp + j);
      STEP(xv.x, 0, dummy) STEP(xv.y, 0, dummy)
      STEP(xv.z, 0, dummy) STEP(xv.w, 0, dummy)
    }
  }
  const float* xp = src + c * CHUNK;
  float* op = out + (size_t)row * T_LEN + c * CHUNK;
#pragma unroll
  for (int j = 0; j < CHUNK; j += 4) {
    float4 xv = *reinterpret_cast<const float4*>(xp + j);
    float4 ov;
    STEP(xv.x, 1, ov.x) STEP(xv.y, 1, ov.y)
    STEP(xv.z, 1, ov.z) STEP(xv.w, 1, ov.w)
    *reinterpret_cast<float4*>(op + j) = ov;
  }
#undef STEP
}

// ---------------------------------------------------------------------------
extern "C" void kernel_launch(void* const* d_in, const int* in_sizes, int n_in,
                              void* d_out, int out_size, void* d_ws, size_t ws_size,
                              hipStream_t stream) {
  const float* x  = (const float*)d_in[0];   // (64, 160000)
  const float* nn = (const float*)d_in[1];   // (64, 160000)
  const float* cx = (const float*)d_in[2];   // (4,) a1,a2,b1,b2
  const float* cn = (const float*)d_in[3];   // (4,)
  float* out = (float*)d_out;                // (128, 160000) flat

  // e1 lives in d_out's storage (5.12 MB << 81.9 MB); pass_a2 fully
  // overwrites d_out afterwards and never reads e1. s1 in ws (5.12 MB).
  double2* e1 = (double2*)d_out;
  double2* s1 = (double2*)d_ws;

  const int total = NROW * NCHUNK;           // 320000
  const int blk = 256;
  const int nb = (total + blk - 1) / blk;    // 1250

  pass_a1<<<nb, blk, 0, stream>>>(x, nn, e1);
  scan1_kernel<<<(NROW * 64 + blk - 1) / blk, blk, 0, stream>>>(e1, s1);
  pass_a2<<<nb, blk, 0, stream>>>(x, nn, s1, out, cx, cn);
}

// Round 4
// 124.857 us; speedup vs baseline: 1.1151x; 1.1151x over previous
//
#include <hip/hip_runtime.h>
#include <math.h>

// Problem geometry
#define T_LEN   160000
#define NROW    128
#define L       64                   // samples per chunk (per-thread serial)
#define W_CH    128                  // warm-up chunks per block
#define O_CH    256                  // own chunks per block (= blockDim)
#define NCHK    (W_CH + O_CH)        // 384
#define T_OWN   (O_CH * L)           // 16384
#define W_SMP   (W_CH * L)           // 8192
#define TILES   10                   // ceil(160000/16384)
#define NBLK    (NROW * TILES)       // 1280

#define XS_FLOATS (2 + W_SMP + T_OWN)    // 24578
#define XS_BYTES  98320                  // padded to 16B
#define E_OFF     XS_BYTES
#define S_OFF     (E_OFF + NCHK * 16)
#define LDS_BYTES (S_OFF + NCHK * 16)    // 110608 <= 160K

// HP biquad: y = x - 2 x1 + x2 + 1.99599 y1 - 0.996 y2
#define C1_HP ( 1.99599)
#define C2_HP (-0.996)

__device__ __forceinline__ int swz(int i) { return i ^ ((i >> 6) & 31); }
__device__ __forceinline__ float clip1f(float v) { return fminf(fmaxf(v, -1.0f), 1.0f); }

__global__ __launch_bounds__(256) void fused_kernel(const float* __restrict__ x,
                                                    const float* __restrict__ nn,
                                                    const float* __restrict__ cx,
                                                    const float* __restrict__ cn,
                                                    float* __restrict__ out) {
  extern __shared__ char lds[];
  float*   xs = (float*)lds;                 // swizzled x tile, later out tile
  double2* e  = (double2*)(lds + E_OFF);     // per-chunk local end states
  double2* s  = (double2*)(lds + S_OFF);     // per-chunk start states (scanned)

  const int tid  = threadIdx.x;
  const int b    = blockIdx.x;
  const int row  = b / TILES, tile = b % TILES;
  const long tile_start = (long)tile * T_OWN;
  const int  g0 = tile * T_OWN - W_SMP;      // global idx of LDS a=2 (may be <0)
  const float* src = (row < 64) ? x + (size_t)row * T_LEN
                                : nn + (size_t)(row - 64) * T_LEN;

  // ---- phase 1: coalesced load of [g0-2, g0+W+T_own) into swizzled LDS ----
  if (tid < 2) {
    int gi = g0 - 2 + tid;
    xs[swz(tid)] = (gi >= 0 && gi < T_LEN) ? src[gi] : 0.0f;
  }
  for (int k = tid; k < (W_SMP + T_OWN) / 4; k += 256) {
    int gi = g0 + 4 * k;                     // 16B-aligned when >= 0
    float4 v = make_float4(0.f, 0.f, 0.f, 0.f);
    if (gi >= 0 && gi < T_LEN) v = *reinterpret_cast<const float4*>(src + gi);
    int a = 2 + 4 * k;
    xs[swz(a)] = v.x; xs[swz(a + 1)] = v.y; xs[swz(a + 2)] = v.z; xs[swz(a + 3)] = v.w;
  }
  __syncthreads();

  // ---- phase 2: local stage-1 end state per chunk (zero y-init, true x-hist)
  for (int c = tid; c < NCHK; c += 256) {
    int a0 = 2 + 64 * c;
    double x1 = (double)xs[swz(a0 - 1)], x2 = (double)xs[swz(a0 - 2)];
    double y1 = 0.0, y2 = 0.0;
#pragma unroll
    for (int j = 0; j < 64; ++j) {
      double xt = (double)xs[swz(a0 + j)];
      double y = (xt - 2.0 * x1 + x2) + (C1_HP * y1 + C2_HP * y2);
      x2 = x1; x1 = xt; y2 = y1; y1 = y;
    }
    e[c] = make_double2(y1, y2);
  }
  __syncthreads();

  // ---- phase 3: one-wave scan of 384 chunk states (M = A^64, f64) ----
  if (tid < 64) {
    double pm2 = 0.0, pm1 = 0.0, p0 = 1.0;
    for (int k = 1; k <= 64; ++k) {
      double pn = C1_HP * p0 + C2_HP * pm1;
      pm2 = pm1; pm1 = p0; p0 = pn;
    }
    const double m00 = p0,  m01 = C2_HP * pm1;
    const double m10 = pm1, m11 = C2_HP * pm2;
    const int base = tid * 6;                 // 64 lanes x 6 = 384
    double f1 = 0.0, f2 = 0.0;
    for (int j = 0; j < 6; ++j) {
      double2 ev = e[base + j];
      double n1 = m00 * f1 + m01 * f2 + ev.x;
      double n2 = m10 * f1 + m11 * f2 + ev.y;
      f1 = n1; f2 = n2;
    }
    // B = M^6
    double q00 = m00 * m00 + m01 * m10, q01 = m00 * m01 + m01 * m11,
           q10 = m10 * m00 + m11 * m10, q11 = m10 * m01 + m11 * m11;       // M^2
    double b00 = q00 * q00 + q01 * q10, b01 = q00 * q01 + q01 * q11,
           b10 = q10 * q00 + q11 * q10, b11 = q10 * q01 + q11 * q11;       // M^4
    { double t00 = b00 * q00 + b01 * q10, t01 = b00 * q01 + b01 * q11,
             t10 = b10 * q00 + b11 * q10, t11 = b10 * q01 + b11 * q11;     // M^6
      b00 = t00; b01 = t01; b10 = t10; b11 = t11; }
    double v1f = f1, v2f = f2;
    for (int off = 1; off < 64; off <<= 1) {
      double u1 = __shfl_up(v1f, off);
      double u2 = __shfl_up(v2f, off);
      if (tid >= off) { v1f += b00 * u1 + b01 * u2; v2f += b10 * u1 + b11 * u2; }
      double t00 = b00 * b00 + b01 * b10, t01 = b00 * b01 + b01 * b11,
             t10 = b10 * b00 + b11 * b10, t11 = b10 * b01 + b11 * b11;
      b00 = t00; b01 = t01; b10 = t10; b11 = t11;
    }
    double g1 = __shfl_up(v1f, 1), g2 = __shfl_up(v2f, 1);
    if (tid == 0) { g1 = 0.0; g2 = 0.0; }
    double s1v = g1, s2v = g2;
    for (int j = 0; j < 6; ++j) {
      int c = base + j;
      s[c] = make_double2(s1v, s2v);
      double2 ev = e[c];
      double n1 = m00 * s1v + m01 * s2v + ev.x;
      double n2 = m10 * s1v + m11 * s2v + ev.y;
      s1v = n1; s2v = n2;
    }
  }
  __syncthreads();

  // ---- phase 4: warm chunk (both stages, no emit) then own chunk (emit) ----
  const float* cf = (row < 64) ? cx : cn;
  const float A1c = cf[0], A2c = cf[1], B1c = cf[2], B2c = cf[3];
  const bool act = (tile_start + 64L * tid) < T_LEN;
  const int co = W_CH + tid, cw = co - 1;
  double x1 = 0.0, x2 = 0.0, y1 = 0.0, y2 = 0.0;
  float v1 = 0.0f, v2 = 0.0f, z1 = 0.0f, z2 = 0.0f;

  if (act) {
    double2 sv = s[cw];
    y1 = sv.x; y2 = sv.y;
    int aw = 2 + 64 * cw;
    x1 = (double)xs[swz(aw - 1)]; x2 = (double)xs[swz(aw - 2)];
    v1 = clip1f((float)sv.x); v2 = clip1f((float)sv.y);
#pragma unroll
    for (int j = 0; j < 64; ++j) {
      double xt = (double)xs[swz(aw + j)];
      double yy = (xt - 2.0 * x1 + x2) + (C1_HP * y1 + C2_HP * y2);
      x2 = x1; x1 = xt; y2 = y1; y1 = yy;
      float vv = clip1f((float)yy);
      float zz = vv + B1c * v1 + B2c * v2 - A1c * z1 - A2c * z2;
      v2 = v1; v1 = vv; z2 = z1; z1 = zz;
    }
  }
  __syncthreads();   // warm reads done; own chunks may now be overwritten
  if (act) {
    int ao = 2 + 64 * co;
#pragma unroll
    for (int j = 0; j < 64; ++j) {
      int aa = swz(ao + j);
      double xt = (double)xs[aa];
      double yy = (xt - 2.0 * x1 + x2) + (C1_HP * y1 + C2_HP * y2);
      x2 = x1; x1 = xt; y2 = y1; y1 = yy;
      float vv = clip1f((float)yy);
      float zz = vv + B1c * v1 + B2c * v2 - A1c * z1 - A2c * z2;
      v2 = v1; v1 = vv; z2 = z1; z1 = zz;
      xs[aa] = clip1f(zz);            // in-place: x slot -> output
    }
  }
  __syncthreads();

  // ---- phase 5: coalesced store of own tile ----
  float* orow = out + (size_t)row * T_LEN;
  for (int k = tid; k < T_OWN / 4; k += 256) {
    long gi = tile_start + 4 * k;
    if (gi < T_LEN) {
      int a = 2 + W_SMP + 4 * k;
      float4 v;
      v.x = xs[swz(a)]; v.y = xs[swz(a + 1)]; v.z = xs[swz(a + 2)]; v.w = xs[swz(a + 3)];
      *reinterpret_cast<float4*>(orow + gi) = v;
    }
  }
}

// ---------------------------------------------------------------------------
extern "C" void kernel_launch(void* const* d_in, const int* in_sizes, int n_in,
                              void* d_out, int out_size, void* d_ws, size_t ws_size,
                              hipStream_t stream) {
  const float* x  = (const float*)d_in[0];   // (64, 160000)
  const float* nn = (const float*)d_in[1];   // (64, 160000)
  const float* cx = (const float*)d_in[2];   // (4,) a1,a2,b1,b2
  const float* cn = (const float*)d_in[3];   // (4,)
  float* out = (float*)d_out;                // (128, 160000) flat

  // allow >64KB dynamic LDS (deterministic, idempotent)
  hipFuncSetAttribute((const void*)fused_kernel,
                      hipFuncAttributeMaxDynamicSharedMemorySize, LDS_BYTES);

  fused_kernel<<<NBLK, 256, LDS_BYTES, stream>>>(x, nn, cx, cn, out);
}

// Round 5
// 105.560 us; speedup vs baseline: 1.3189x; 1.1828x over previous
//
#include <hip/hip_runtime.h>
#include <math.h>

// Problem geometry
#define T_LEN   160000
#define NROW    128       // 64 rows of x then 64 rows of n
#define CHUNK   64        // samples per chunk
#define NCHUNK  2500      // CHUNK*NCHUNK == T_LEN
#define OWN     40        // chunks per lane in scan (64*40 = 2560 >= 2500)
#define O_CH    256       // own chunks per emit block
#define T_OWN   (O_CH * CHUNK)   // 16384
#define TILES   10               // ceil(2500/256)
#define NBLK    (NROW * TILES)   // 1280

// LDS tile for emit: [2 history][64 warm][16384 own]
#define XS_FLOATS 16450
#define XS_PAD    16464
#define LDS_BYTES (XS_PAD * 4)   // 65856 B -> 2 blocks/CU

// HP biquad: y = x - 2 x1 + x2 + 1.99599 y1 - 0.996 y2
#define C1_HP ( 1.99599)
#define C2_HP (-0.996)

__device__ __forceinline__ int swz(int i) { return i ^ ((i >> 6) & 31); }
__device__ __forceinline__ float clip1f(float v) { return fminf(fmaxf(v, -1.0f), 1.0f); }

// ---------------------------------------------------------------------------
// pass_a1: per (row, chunk) LOCAL stage-1 end state (zero y-init, true x-hist).
// ---------------------------------------------------------------------------
__global__ __launch_bounds__(256) void pass_a1(const float* __restrict__ x,
                                               const float* __restrict__ nn,
                                               double2* __restrict__ e1) {
  int g = blockIdx.x * blockDim.x + threadIdx.x;
  if (g >= NROW * NCHUNK) return;
  int row = g / NCHUNK, c = g % NCHUNK;
  const float* src = (row < 64) ? (x + (size_t)row * T_LEN)
                                : (nn + (size_t)(row - 64) * T_LEN);
  const float* xp = src + c * CHUNK;
  double x1 = 0.0, x2 = 0.0;
  if (c) { x1 = (double)xp[-1]; x2 = (double)xp[-2]; }
  double y1 = 0.0, y2 = 0.0;
#pragma unroll
  for (int j = 0; j < CHUNK; j += 4) {
    float4 xv = *reinterpret_cast<const float4*>(xp + j);
#define A1STEP(XF) { double xt = (double)(XF); \
    double y = (xt - 2.0 * x1 + x2) + (C1_HP * y1 + C2_HP * y2); \
    x2 = x1; x1 = xt; y2 = y1; y1 = y; }
    A1STEP(xv.x) A1STEP(xv.y) A1STEP(xv.z) A1STEP(xv.w)
#undef A1STEP
  }
  e1[g] = make_double2(y1, y2);
}

// ---------------------------------------------------------------------------
// scan1: wave-parallel per-row combine, s_{c+1} = M s_c + e_c, M = A_hp^64.
// Emits chunk-START true states s[c].
// ---------------------------------------------------------------------------
__global__ __launch_bounds__(256) void scan1_kernel(const double2* __restrict__ e,
                                                    double2* __restrict__ s) {
  int tid = blockIdx.x * blockDim.x + threadIdx.x;
  int row = tid >> 6;
  int lane = tid & 63;
  if (row >= NROW) return;
  double pm2 = 0.0, pm1 = 0.0, p0 = 1.0;
#pragma unroll
  for (int k = 1; k <= CHUNK; ++k) {
    double pn = C1_HP * p0 + C2_HP * pm1;
    pm2 = pm1; pm1 = p0; p0 = pn;
  }
  const double m00 = p0,  m01 = C2_HP * pm1;
  const double m10 = pm1, m11 = C2_HP * pm2;
  const double2* ep = e + (size_t)row * NCHUNK;
  const int base = lane * OWN;
  double f1 = 0.0, f2 = 0.0;
  for (int j = 0; j < OWN; ++j) {
    int c = base + j;
    double2 ev = (c < NCHUNK) ? ep[c] : make_double2(0.0, 0.0);
    double n1 = m00 * f1 + m01 * f2 + ev.x;
    double n2 = m10 * f1 + m11 * f2 + ev.y;
    f1 = n1; f2 = n2;
  }
  // B = M^OWN by binary exponentiation
  double b00 = m00, b01 = m01, b10 = m10, b11 = m11;
  double r00 = 1.0, r01 = 0.0, r10 = 0.0, r11 = 1.0;
  int e40 = OWN;
  while (e40) {
    if (e40 & 1) {
      double t00 = b00 * r00 + b01 * r10, t01 = b00 * r01 + b01 * r11;
      double t10 = b10 * r00 + b11 * r10, t11 = b10 * r01 + b11 * r11;
      r00 = t00; r01 = t01; r10 = t10; r11 = t11;
    }
    double q00 = b00 * b00 + b01 * b10, q01 = b00 * b01 + b01 * b11;
    double q10 = b10 * b00 + b11 * b10, q11 = b10 * b01 + b11 * b11;
    b00 = q00; b01 = q01; b10 = q10; b11 = q11;
    e40 >>= 1;
  }
  b00 = r00; b01 = r01; b10 = r10; b11 = r11;
  double v1 = f1, v2 = f2;
#pragma unroll
  for (int off = 1; off < 64; off <<= 1) {
    double u1 = __shfl_up(v1, off);
    double u2 = __shfl_up(v2, off);
    if (lane >= off) {
      v1 += b00 * u1 + b01 * u2;
      v2 += b10 * u1 + b11 * u2;
    }
    double q00 = b00 * b00 + b01 * b10, q01 = b00 * b01 + b01 * b11;
    double q10 = b10 * b00 + b11 * b10, q11 = b10 * b01 + b11 * b11;
    b00 = q00; b01 = q01; b10 = q10; b11 = q11;
  }
  double g1 = __shfl_up(v1, 1);
  double g2 = __shfl_up(v2, 1);
  if (lane == 0) { g1 = 0.0; g2 = 0.0; }
  double2* sp = s + (size_t)row * NCHUNK;
  double s1v = g1, s2v = g2;
  for (int j = 0; j < OWN; ++j) {
    int c = base + j;
    if (c < NCHUNK) {
      sp[c] = make_double2(s1v, s2v);
      double2 ev = ep[c];
      double n1 = m00 * s1v + m01 * s2v + ev.x;
      double n2 = m10 * s1v + m11 * s2v + ev.y;
      s1v = n1; s2v = n2;
    }
  }
}

// ---------------------------------------------------------------------------
// emit: per block = (row, tile of 256 chunks). x tile staged in LDS (swizzled,
// coalesced load). Each thread: seed stage-1 EXACTLY from s1[c-1], run 64-
// sample warm chunk (stage-2 converges, pole^64 ~ 7e-6), then own chunk,
// overwriting its x slots in LDS with final output; coalesced store.
// ---------------------------------------------------------------------------
__global__ __launch_bounds__(256) void emit_kernel(const float* __restrict__ x,
                                                   const float* __restrict__ nn,
                                                   const double2* __restrict__ s1,
                                                   const float* __restrict__ cx,
                                                   const float* __restrict__ cn,
                                                   float* __restrict__ out) {
  __shared__ float xs[XS_PAD];
  const int tid = threadIdx.x;
  const int b = blockIdx.x;
  const int row = b / TILES, tile = b % TILES;
  const int c0 = tile * O_CH;                 // first own chunk
  const long tile_start = (long)c0 * CHUNK;
  const long g0 = tile_start - CHUNK;         // global index of LDS a=2
  const float* src = (row < 64) ? x + (size_t)row * T_LEN
                                : nn + (size_t)(row - 64) * T_LEN;

  // ---- load [g0-2, g0 + 64 + 16384) into swizzled LDS ----
  if (tid < 2) {
    long gi = g0 - 2 + tid;
    xs[swz(tid)] = (gi >= 0 && gi < T_LEN) ? src[gi] : 0.0f;
  }
  for (int k = tid; k < (CHUNK + T_OWN) / 4; k += 256) {
    long gi = g0 + 4 * k;
    float4 v = make_float4(0.f, 0.f, 0.f, 0.f);
    if (gi >= 0 && gi < T_LEN) v = *reinterpret_cast<const float4*>(src + gi);
    int a = 2 + 4 * k;
    xs[swz(a)] = v.x; xs[swz(a + 1)] = v.y; xs[swz(a + 2)] = v.z; xs[swz(a + 3)] = v.w;
  }
  __syncthreads();

  const int c = c0 + tid;
  const bool act = (c < NCHUNK);
  const float* cf = (row < 64) ? cx : cn;
  const float A1c = cf[0], A2c = cf[1], B1c = cf[2], B2c = cf[3];

  double x1 = 0.0, x2 = 0.0, y1 = 0.0, y2 = 0.0;
  float v1 = 0.0f, v2 = 0.0f, z1 = 0.0f, z2 = 0.0f;

  if (act) {
    if (c > 0) {
      double2 sv = s1[(size_t)row * NCHUNK + (c - 1)];
      y1 = sv.x; y2 = sv.y;
      v1 = clip1f((float)sv.x); v2 = clip1f((float)sv.y);
    }
    const int aw = (tid == 0) ? 2 : 66 + CHUNK * (tid - 1);
    x1 = (double)xs[swz(aw - 1)]; x2 = (double)xs[swz(aw - 2)];
#pragma unroll
    for (int j = 0; j < CHUNK; ++j) {
      double xt = (double)xs[swz(aw + j)];
      double yy = (xt - 2.0 * x1 + x2) + (C1_HP * y1 + C2_HP * y2);
      x2 = x1; x1 = xt; y2 = y1; y1 = yy;
      float vv = clip1f((float)yy);
      float zz = vv + B1c * v1 + B2c * v2 - A1c * z1 - A2c * z2;
      v2 = v1; v1 = vv; z2 = z1; z1 = zz;
    }
  }
  __syncthreads();   // warm reads done; own chunks may be overwritten now
  if (act) {
    const int ao = 66 + CHUNK * tid;
#pragma unroll
    for (int j = 0; j < CHUNK; ++j) {
      int aa = swz(ao + j);
      double xt = (double)xs[aa];
      double yy = (xt - 2.0 * x1 + x2) + (C1_HP * y1 + C2_HP * y2);
      x2 = x1; x1 = xt; y2 = y1; y1 = yy;
      float vv = clip1f((float)yy);
      float zz = vv + B1c * v1 + B2c * v2 - A1c * z1 - A2c * z2;
      v2 = v1; v1 = vv; z2 = z1; z1 = zz;
      xs[aa] = clip1f(zz);
    }
  }
  __syncthreads();

  // ---- coalesced store of own tile ----
  float* orow = out + (size_t)row * T_LEN;
  for (int k = tid; k < T_OWN / 4; k += 256) {
    long gi = tile_start + 4 * k;
    if (gi < T_LEN) {
      int a = 66 + 4 * k;
      float4 v;
      v.x = xs[swz(a)]; v.y = xs[swz(a + 1)]; v.z = xs[swz(a + 2)]; v.w = xs[swz(a + 3)];
      *reinterpret_cast<float4*>(orow + gi) = v;
    }
  }
}

// ---------------------------------------------------------------------------
extern "C" void kernel_launch(void* const* d_in, const int* in_sizes, int n_in,
                              void* d_out, int out_size, void* d_ws, size_t ws_size,
                              hipStream_t stream) {
  const float* x  = (const float*)d_in[0];   // (64, 160000)
  const float* nn = (const float*)d_in[1];   // (64, 160000)
  const float* cx = (const float*)d_in[2];   // (4,) a1,a2,b1,b2
  const float* cn = (const float*)d_in[3];   // (4,)
  float* out = (float*)d_out;                // (128, 160000) flat

  // e1 aliases d_out (5.12 MB << 81.9 MB; consumed by scan1 before emit
  // overwrites d_out). s1 in ws (5.12 MB), read by emit while out is written.
  double2* e1 = (double2*)d_out;
  double2* s1 = (double2*)d_ws;

  const int total = NROW * NCHUNK;           // 320000
  const int blk = 256;
  const int nb = (total + blk - 1) / blk;    // 1250

  pass_a1<<<nb, blk, 0, stream>>>(x, nn, e1);
  scan1_kernel<<<(NROW * 64 + blk - 1) / blk, blk, 0, stream>>>(e1, s1);
  emit_kernel<<<NBLK, blk, 0, stream>>>(x, nn, s1, cx, cn, out);
}